// Round 13
// baseline (72.399 us; speedup 1.0000x reference)
//
#include <hip/hip_runtime.h>

#define TSTEPS 128
#define NBATCH 2048
#define DIN    32
#define NROWS  (TSTEPS * NBATCH)
#define INV_PI 0.31830988618379067f

// ---- quad-scoped DPP permute (acts within each group of 4 lanes) ----
template <int CTRL>
__device__ __forceinline__ float qperm(float v) {
    return __int_as_float(
        __builtin_amdgcn_mov_dpp(__float_as_int(v), CTRL, 0xF, 0xF, true));
}
// quad_perm ctrl: sel3<<6|sel2<<4|sel1<<2|sel0.
//  0x90 = [0,0,1,2] shift-up-1 ; 0x44 = [0,1,0,1] shift-up-2
//  0x00/0x55/0xAA/0xFF = broadcast quad-lane 0/1/2/3

// ======================= Kernel A: x-projection GEMM =======================
// ws[row*16 + i*4 + g] = (1/pi)*(b_g[i] + x[row,:] . W_g[i,0:32])
// i-major, gate order g: 0=f,1=i,2=u,3=o.  row = t*NBATCH + b.
extern "C" __global__ void __launch_bounds__(256)
xproj_kernel(const float* __restrict__ x,
             const float* __restrict__ Wf, const float* __restrict__ bfp,
             const float* __restrict__ Wi, const float* __restrict__ bip,
             const float* __restrict__ Wu, const float* __restrict__ bup,
             const float* __restrict__ Wo, const float* __restrict__ bop,
             float* __restrict__ ws)
{
    __shared__ float4 WL[16 * 8];
    __shared__ float  bias[16];
    const int tid = threadIdx.x;
    float* WLf = (float*)WL;
    for (int idx = tid; idx < 512; idx += 256) {
        int rr = idx >> 5, k = idx & 31;          // rr = i*4+g
        int i = rr >> 2, g = rr & 3;
        const float* W = (g == 0) ? Wf : (g == 1) ? Wi : (g == 2) ? Wu : Wo;
        WLf[rr * 32 + k] = W[i * 36 + k] * INV_PI;
    }
    if (tid < 16) {
        int i = tid >> 2, g = tid & 3;
        const float* bp = (g == 0) ? bfp : (g == 1) ? bip : (g == 2) ? bup : bop;
        bias[tid] = bp[i] * INV_PI;
    }
    __syncthreads();

    const int row0 = blockIdx.x * 512 + tid;      // 2 rows/thread, stride 256
    const float4* xv = reinterpret_cast<const float4*>(x);
    float4 xa[2][8];
#pragma unroll
    for (int j = 0; j < 2; ++j) {
        int row = row0 + j * 256;
#pragma unroll
        for (int k = 0; k < 8; ++k) xa[j][k] = xv[row * 8 + k];
    }
    float acc[2][16];
#pragma unroll
    for (int rr = 0; rr < 16; ++rr) {
        float4 w[8];
#pragma unroll
        for (int k = 0; k < 8; ++k) w[k] = WL[rr * 8 + k];
#pragma unroll
        for (int j = 0; j < 2; ++j) {
            float s = bias[rr];
#pragma unroll
            for (int k = 0; k < 8; ++k) {
                s = fmaf(xa[j][k].x, w[k].x, s);
                s = fmaf(xa[j][k].y, w[k].y, s);
                s = fmaf(xa[j][k].z, w[k].z, s);
                s = fmaf(xa[j][k].w, w[k].w, s);
            }
            acc[j][rr] = s;
        }
    }
    float4* wsv = reinterpret_cast<float4*>(ws);
#pragma unroll
    for (int j = 0; j < 2; ++j) {
        int row = row0 + j * 256;
#pragma unroll
        for (int ii = 0; ii < 4; ++ii)
            wsv[row * 4 + ii] =
                make_float4(acc[j][ii * 4 + 0], acc[j][ii * 4 + 1],
                            acc[j][ii * 4 + 2], acc[j][ii * 4 + 3]);
    }
}

// ===================== Kernel B: serial recurrence v3 =====================
// 512 blocks x 64 lanes, 4 batches/block. Stage block's whole X slice
// (32 KB) into LDS up-front with all 64 lanes (latency amortized once),
// then lanes 0..15 run the in-lane-gates chain (quad = batch, lane = i):
// prefix-product DPP depth 2, h-broadcast depth 1, c/h math in-lane.
extern "C" __global__ void __launch_bounds__(64)
recur_kernel(const float* __restrict__ ws,
             const float* __restrict__ Wf, const float* __restrict__ Wi,
             const float* __restrict__ Wu, const float* __restrict__ Wo,
             float* __restrict__ out)
{
    __shared__ float4 Xls4[TSTEPS * 16];          // 32 KB: [t*16 + b*4 + i]
    __shared__ float  Ols[TSTEPS * 16];           // 8 KB:  [t][b*4 + i]

    const int l  = threadIdx.x;
    const int B0 = blockIdx.x * 4;

    // ---- burst-stage X slice: 4 rounds x 8 float4/lane (MLP-amortized) ----
    const float4* wsv = reinterpret_cast<const float4*>(ws);
#pragma unroll
    for (int jr = 0; jr < 4; ++jr) {
        float4 v[8];
#pragma unroll
        for (int m = 0; m < 8; ++m) {
            int f4 = jr * 512 + m * 64 + l;       // 0..2047 = t*16 + rem
            int t = f4 >> 4, rem = f4 & 15;
            v[m] = wsv[(size_t)t * (NBATCH * 4) + (size_t)B0 * 4 + rem];
        }
#pragma unroll
        for (int m = 0; m < 8; ++m) Xls4[jr * 512 + m * 64 + l] = v[m];
    }

    const int bl = l >> 2, i = l & 3;             // used by lanes < 16
    const int bg = B0 + bl;
    const bool m1 = (i >= 1), m2 = (i >= 2);

    // h-weights: wh*[e] = W_*[i][32+e]/pi  (h_e broadcast from quad lane e)
    float whf[4], whi[4], whu[4], who[4];
#pragma unroll
    for (int e = 0; e < 4; ++e) {
        const int col = (i & 3) * 36 + 32 + e;
        whf[e] = Wf[col] * INV_PI;
        whi[e] = Wi[col] * INV_PI;
        whu[e] = Wu[col] * INV_PI;
        who[e] = Wo[col] * INV_PI;
    }

    // sigmoid(q) on [0,1], deg-3;  tanh(q) on [0,1], deg-3
    const float S0 = 0.499971f, S1 = 0.250882f, S2 = -0.004115f, S3 = -0.015724f;
    const float U0 = 0.0008346f, U1 = 1.036967f, U2 = -0.175884f, U3 = -0.099350f;
    // tanh(c) for |c|<=2.08: c*P(c^2), deg-4
    const float T0 = 0.99827f, T1 = -0.313542f, T2 = 0.0915168f,
                T3 = -0.0160296f, T4 = 0.0011677f;

    float h0 = 0.f, h1 = 0.f, h2 = 0.f, h3 = 0.f, cst = 0.f, hlast = 0.f;

    __syncthreads();   // X staged

    if (l < 16) {
        // 4-deep LDS->reg prefetch ring
        float4 xr[4];
#pragma unroll
        for (int k = 0; k < 4; ++k) xr[k] = Xls4[k * 16 + l];

        for (int t0 = 0; t0 < TSTEPS; t0 += 4) {
#pragma unroll
            for (int k = 0; k < 4; ++k) {
                const int t = t0 + k;
                float4 xp = xr[k];
                int tn = t + 4;  if (tn > TSTEPS - 1) tn = TSTEPS - 1;
                xr[k] = Xls4[tn * 16 + l];

                // pre-activations /pi — 4 gates in-lane (ILP 4)
                float Af = fmaf(whf[0], h0, xp.x), Bf = fmaf(whf[1], h1, whf[2] * h2);
                float Ag = fmaf(whi[0], h0, xp.y), Bg = fmaf(whi[1], h1, whi[2] * h2);
                float Au = fmaf(whu[0], h0, xp.z), Bu = fmaf(whu[1], h1, whu[2] * h2);
                float Ao = fmaf(who[0], h0, xp.w), Bo = fmaf(who[1], h1, who[2] * h2);
                float p0 = fmaf(whf[3], h3, Af) + Bf;
                float p1 = fmaf(whi[3], h3, Ag) + Bg;
                float p2 = fmaf(whu[3], h3, Au) + Bu;
                float p3 = fmaf(who[3], h3, Ao) + Bo;

                // cos^2(pre) = 0.5 + 0.5*cos_rev(pre/pi)  (4x ILP)
                float q0 = fmaf(0.5f, __builtin_amdgcn_cosf(__builtin_amdgcn_fractf(p0)), 0.5f);
                float q1 = fmaf(0.5f, __builtin_amdgcn_cosf(__builtin_amdgcn_fractf(p1)), 0.5f);
                float q2 = fmaf(0.5f, __builtin_amdgcn_cosf(__builtin_amdgcn_fractf(p2)), 0.5f);
                float q3 = fmaf(0.5f, __builtin_amdgcn_cosf(__builtin_amdgcn_fractf(p3)), 0.5f);

                // prefix product over i within quad — DPP depth 2
                float s0 = qperm<0x90>(q0);  q0 *= m1 ? s0 : 1.0f;
                float s1 = qperm<0x90>(q1);  q1 *= m1 ? s1 : 1.0f;
                float s2 = qperm<0x90>(q2);  q2 *= m1 ? s2 : 1.0f;
                float s3 = qperm<0x90>(q3);  q3 *= m1 ? s3 : 1.0f;
                float u0 = qperm<0x44>(q0);  q0 *= m2 ? u0 : 1.0f;
                float u1 = qperm<0x44>(q1);  q1 *= m2 ? u1 : 1.0f;
                float u2 = qperm<0x44>(q2);  q2 *= m2 ? u2 : 1.0f;
                float u3 = qperm<0x44>(q3);  q3 *= m2 ? u3 : 1.0f;

                // activations in-lane (ILP 4)
                float yf = fmaf(fmaf(fmaf(S3, q0, S2), q0, S1), q0, S0);
                float yi = fmaf(fmaf(fmaf(S3, q1, S2), q1, S1), q1, S0);
                float yu = fmaf(fmaf(fmaf(U3, q2, U2), q2, U1), q2, U0);
                float yo = fmaf(fmaf(fmaf(S3, q3, S2), q3, S1), q3, S0);

                // c and h fully in-lane (c_i owned by lane i)
                cst = fmaf(yf, cst, yi * yu);
                float tt = cst * cst;
                float gg = fmaf(fmaf(fmaf(fmaf(T4, tt, T3), tt, T2), tt, T1), tt, T0);
                float hn = yo * (cst * gg);
                hlast = hn;

                Ols[t * 16 + l] = hn;             // LDS store, off-chain

                // h-broadcast within quad: depth-1 DPP
                h0 = qperm<0x00>(hn);
                h1 = qperm<0x55>(hn);
                h2 = qperm<0xAA>(hn);
                h3 = qperm<0xFF>(hn);
            }
        }
    }

    __syncthreads();   // Ols complete

    // ---- flush: 8 float4 per lane, coalesced (all 64 lanes) ----
    float4* outv = reinterpret_cast<float4*>(out);
    const float4* Ols4 = reinterpret_cast<const float4*>(Ols);
#pragma unroll
    for (int m = 0; m < 8; ++m) {
        int f4 = m * 64 + l;                      // 0..511 = t*4 + b
        int t = f4 >> 2, b = f4 & 3;
        outv[(size_t)t * NBATCH + B0 + b] = Ols4[f4];
    }

    if (l < 16) {
        const size_t off = (size_t)TSTEPS * NBATCH * 4;
        out[off + (size_t)bg * 4 + i] = hlast;                     // final hx
        out[off + (size_t)NBATCH * 4 + (size_t)bg * 4 + i] = cst;  // final cx
    }
}

extern "C" void kernel_launch(void* const* d_in, const int* in_sizes, int n_in,
                              void* d_out, int out_size, void* d_ws, size_t ws_size,
                              hipStream_t stream) {
    (void)in_sizes; (void)n_in; (void)out_size;
    const float* x  = (const float*)d_in[0];
    const float* Wf = (const float*)d_in[1];
    const float* bf = (const float*)d_in[2];
    // d_in[3] = pf: RZ phases drop out of the measurement -> unused
    const float* Wi = (const float*)d_in[4];
    const float* bi = (const float*)d_in[5];
    const float* Wu = (const float*)d_in[7];
    const float* bu = (const float*)d_in[8];
    const float* Wo = (const float*)d_in[10];
    const float* bo = (const float*)d_in[11];
    float* out = (float*)d_out;

    float* ws = (float*)d_ws;   // 16.78 MB needed; harness ws is larger
    hipLaunchKernelGGL(xproj_kernel, dim3(NROWS / 512), dim3(256), 0, stream,
                       x, Wf, bf, Wi, bi, Wu, bu, Wo, bo, ws);
    hipLaunchKernelGGL(recur_kernel, dim3(NBATCH / 4), dim3(64), 0, stream,
                       ws, Wf, Wi, Wu, Wo, out);
}

// Round 14
// 38.643 us; speedup vs baseline: 1.8735x; 1.8735x over previous
//
#include <hip/hip_runtime.h>

#define TSTEPS 128
#define NBATCH 2048
#define DIN    32
#define NROWS  (TSTEPS * NBATCH)
#define INV_PI 0.31830988618379067f

// ---- DPP helpers ----
template <int CTRL>
__device__ __forceinline__ float qperm(float v) {   // quad_perm, all lanes valid
    return __int_as_float(
        __builtin_amdgcn_mov_dpp(__float_as_int(v), CTRL, 0xF, 0xF, true));
}
template <int CTRL>
__device__ __forceinline__ float dpp_z(float v) {   // row shift, invalid -> 0
    return __int_as_float(__builtin_amdgcn_update_dpp(
        0, __float_as_int(v), CTRL, 0xF, 0xF, true));
}
template <int CTRL>
__device__ __forceinline__ float dpp_k(float oldv, float v) { // invalid -> keep old
    return __int_as_float(__builtin_amdgcn_update_dpp(
        __float_as_int(oldv), __float_as_int(v), CTRL, 0xF, 0xF, false));
}
// ctrl: quad_perm 0x00-0xFF; row_shl:N = 0x100+N; row_shr:N = 0x110+N.
// 0x1B = quad XOR-3.

// ================= Kernel A v2: x-projection, coalesced via LDS =================
// ws[row*16 + g2*4 + i] = (1/pi)*(b_g[i] + x[row,:] . W_g[i,0:32])
// gate order g2: 0=f, 1=o, 2=i, 3=u.   row = t*NBATCH + b.
// 1024 blocks x 256 thr, 256 rows/block. Loads are lane-contiguous float4
// (1KB/instruction); x-tile staged in LDS with 33-float padded rows so the
// compute-phase per-row b32 reads are bank-conflict-free ((r+e)%32 distinct).
extern "C" __global__ void __launch_bounds__(256)
xproj_kernel(const float* __restrict__ x,
             const float* __restrict__ Wf, const float* __restrict__ bfp,
             const float* __restrict__ Wi, const float* __restrict__ bip,
             const float* __restrict__ Wu, const float* __restrict__ bup,
             const float* __restrict__ Wo, const float* __restrict__ bop,
             float* __restrict__ ws)
{
    __shared__ float4 WL[16 * 8];          // 2 KB
    __shared__ float  bias[16];
    __shared__ float  Xt[256 * 33];        // 33.8 KB padded x-tile

    const int tid = threadIdx.x;
    float* WLf = (float*)WL;
    for (int idx = tid; idx < 512; idx += 256) {
        int rr = idx >> 5, k = idx & 31;             // rr = g2*4+i
        int g2 = rr >> 2, i = rr & 3;
        const float* W = (g2 == 0) ? Wf : (g2 == 1) ? Wo : (g2 == 2) ? Wi : Wu;
        WLf[rr * 32 + k] = W[i * 36 + k] * INV_PI;
    }
    if (tid < 16) {
        int g2 = tid >> 2, i = tid & 3;
        const float* bp = (g2 == 0) ? bfp : (g2 == 1) ? bop : (g2 == 2) ? bip : bup;
        bias[tid] = bp[i] * INV_PI;
    }

    // ---- stage 256 rows coalesced: 8 rounds x 256 lanes x float4 ----
    const int rowbase = blockIdx.x * 256;
    const float4* xv = reinterpret_cast<const float4*>(x) + (size_t)rowbase * 8;
#pragma unroll
    for (int rnd = 0; rnd < 8; ++rnd) {
        int f4 = rnd * 256 + tid;                    // 0..2047, lane-contiguous
        float4 v = xv[f4];
        int row = f4 >> 3, el = f4 & 7;
        float* dst = &Xt[row * 33 + el * 4];
        dst[0] = v.x; dst[1] = v.y; dst[2] = v.z; dst[3] = v.w;
    }
    __syncthreads();

    // ---- compute 1 row/thread from LDS (conflict-free b32 reads) ----
    float xrow[32];
#pragma unroll
    for (int e = 0; e < 32; ++e) xrow[e] = Xt[tid * 33 + e];

    float acc[16];
#pragma unroll
    for (int rr = 0; rr < 16; ++rr) {
        float s = bias[rr];
#pragma unroll
        for (int k = 0; k < 8; ++k) {
            float4 w = WL[rr * 8 + k];               // wave-uniform broadcast
            s = fmaf(xrow[k * 4 + 0], w.x, s);
            s = fmaf(xrow[k * 4 + 1], w.y, s);
            s = fmaf(xrow[k * 4 + 2], w.z, s);
            s = fmaf(xrow[k * 4 + 3], w.w, s);
        }
        acc[rr] = s;
    }

    float4* wsv = reinterpret_cast<float4*>(ws);
    const int row = rowbase + tid;
#pragma unroll
    for (int g2 = 0; g2 < 4; ++g2)
        wsv[row * 4 + g2] = make_float4(acc[g2 * 4 + 0], acc[g2 * 4 + 1],
                                        acc[g2 * 4 + 2], acc[g2 * 4 + 3]);
}

// ============== Kernel B: serial recurrence (R7-best, verbatim) ==============
// 16 lanes per batch: lane = bl*16 + r, r = g*4+i (g: 0=f,1=o,2=i,3=u).
// 4 batches/wave, 1 wave/block, 512 blocks.
// Loop has ZERO global-memory ops: X pre-staged in LDS, outputs staged in LDS.
extern "C" __global__ void __launch_bounds__(64)
recur_kernel(const float* __restrict__ ws,
             const float* __restrict__ Wf, const float* __restrict__ Wi,
             const float* __restrict__ Wu, const float* __restrict__ Wo,
             float* __restrict__ out)
{
    __shared__ float Xls[TSTEPS * 64];    // 32 KB: [t][bl*16 + r]
    __shared__ float Ols[TSTEPS * 16];    // 8 KB:  [t][bl*4 + i]

    const int l  = threadIdx.x;
    const int bl = l >> 4;
    const int r  = l & 15;
    const int g  = r >> 2;                // 0=f,1=o,2=i,3=u
    const int i  = r & 3;
    const int B0g = blockIdx.x * 4;
    const int bg  = B0g + bl;
    const bool m1 = (i >= 1), m2 = (i >= 2);

    // ---- stage X slice into LDS: 2 rounds x 16 float4 per lane ----
    const float4* wsv = reinterpret_cast<const float4*>(ws);
    float4* Xls4 = reinterpret_cast<float4*>(Xls);
#pragma unroll
    for (int j = 0; j < 2; ++j) {
        float4 v[16];
#pragma unroll
        for (int m = 0; m < 16; ++m) {
            int f4 = j * 1024 + m * 64 + l;       // 0..2047
            int t = f4 >> 4, c4 = f4 & 15;
            v[m] = wsv[(size_t)t * (NBATCH * 4) + B0g * 4 + c4];
        }
#pragma unroll
        for (int m = 0; m < 16; ++m) Xls4[j * 1024 + m * 64 + l] = v[m];
    }

    const float* Wg = (g == 0) ? Wf : (g == 1) ? Wo : (g == 2) ? Wi : Wu;
    float wh0 = Wg[i * 36 + 32 + (i ^ 0)] * INV_PI;
    float wh1 = Wg[i * 36 + 32 + (i ^ 1)] * INV_PI;
    float wh2 = Wg[i * 36 + 32 + (i ^ 2)] * INV_PI;
    float wh3 = Wg[i * 36 + 32 + (i ^ 3)] * INV_PI;

    // gate activation: deg-3 poly on q in [0,1]. g!=3: sigmoid; g==3: tanh.
    const bool isU = (g == 3);
    const float c0 = isU ? 0.0008346f : 0.499971f;
    const float c1 = isU ? 1.036967f  : 0.250882f;
    const float c2 = isU ? -0.175884f : -0.004115f;
    const float c3 = isU ? -0.099350f : -0.015724f;
    // tanh(c) for |c|<=2.08: c*P(c^2), deg-4
    const float T0 = 0.99827f,  T1 = -0.313542f, T2 = 0.0915168f,
                T3 = -0.0160296f, T4 = 0.0011677f;

    float ha = 0.f, hx1 = 0.f, hx2 = 0.f, hx3 = 0.f, cst = 0.f;

    __syncthreads();   // LDS X visible across lanes

    auto qstep = [&](float xp, int t) {
        float A  = fmaf(wh0, ha,  xp);
        float Bt = fmaf(wh1, hx1, wh2 * hx2);
        float p  = fmaf(wh3, hx3, A) + Bt;
        float fr = __builtin_amdgcn_fractf(p);
        float cs = __builtin_amdgcn_cosf(fr);
        float q  = fmaf(0.5f, cs, 0.5f);
        float s1 = qperm<0x90>(q);  q *= m1 ? s1 : 1.0f;
        float s2 = qperm<0x44>(q);  q *= m2 ? s2 : 1.0f;
        float y  = fmaf(fmaf(fmaf(c3, q, c2), q, c1), q, c0);
        float t1 = dpp_z<0x104>(y);          // f<-sig_o, i<-tanh_u
        float m_ = y * t1;                   // i-lanes: sig_i * tanh_u
        float t2 = dpp_z<0x108>(m_);         // f-lanes <- i*u
        cst = fmaf(y, cst, t2);              // f-lanes: f*c + i*u
        float tt = cst * cst;
        float gg = fmaf(fmaf(fmaf(fmaf(T4, tt, T3), tt, T2), tt, T1), tt, T0);
        float th = cst * gg;
        float hn = t1 * th;                  // o * tanh(c) at f-lanes
        if (r < 4) Ols[t * 16 + bl * 4 + r] = hn;
        float d1 = dpp_k<0x114>(hn, hn);     // lanes 4..7  <- 0..3
        float d2 = dpp_k<0x118>(d1, d1);     // lanes 8..15 <- 0..7
        ha  = d2;
        hx1 = qperm<0xB1>(d2);
        hx2 = qperm<0x4E>(d2);
        hx3 = qperm<0x1B>(d2);
    };

    // 4-deep LDS->reg prefetch ring
    float xr[4];
#pragma unroll
    for (int k = 0; k < 4; ++k) xr[k] = Xls[k * 64 + l];

    for (int t0 = 0; t0 < TSTEPS; t0 += 4) {
#pragma unroll
        for (int k = 0; k < 4; ++k) {
            const int t = t0 + k;
            float xp = xr[k];
            int tn = t + 4;  if (tn > TSTEPS - 1) tn = TSTEPS - 1;
            xr[k] = Xls[tn * 64 + l];
            qstep(xp, t);
        }
    }

    __syncthreads();   // Ols complete

    // ---- flush outputs: 8 float4 per lane, coalesced ----
    float4* outv = reinterpret_cast<float4*>(out);
    const float4* Ols4 = reinterpret_cast<const float4*>(Ols);
#pragma unroll
    for (int m = 0; m < 8; ++m) {
        int f4 = m * 64 + l;                 // 0..511
        int t = f4 >> 2, q4 = f4 & 3;
        outv[(size_t)t * (NBATCH) + B0g + q4] = Ols4[f4];
    }

    const size_t off = (size_t)TSTEPS * NBATCH * 4;
    if (r < 4) {
        out[off + (size_t)bg * 4 + r] = ha;                       // final hx
        out[off + (size_t)NBATCH * 4 + (size_t)bg * 4 + r] = cst; // final cx
    }
}

extern "C" void kernel_launch(void* const* d_in, const int* in_sizes, int n_in,
                              void* d_out, int out_size, void* d_ws, size_t ws_size,
                              hipStream_t stream) {
    (void)in_sizes; (void)n_in; (void)out_size; (void)ws_size;
    const float* x  = (const float*)d_in[0];
    const float* Wf = (const float*)d_in[1];
    const float* bf = (const float*)d_in[2];
    // d_in[3] = pf: RZ phases drop out of the measurement -> unused
    const float* Wi = (const float*)d_in[4];
    const float* bi = (const float*)d_in[5];
    const float* Wu = (const float*)d_in[7];
    const float* bu = (const float*)d_in[8];
    const float* Wo = (const float*)d_in[10];
    const float* bo = (const float*)d_in[11];
    float* out = (float*)d_out;

    float* ws = (float*)d_ws;   // 16.78 MB needed; harness ws is larger
    hipLaunchKernelGGL(xproj_kernel, dim3(NROWS / 256), dim3(256), 0, stream,
                       x, Wf, bf, Wi, bi, Wu, bu, Wo, bo, ws);
    hipLaunchKernelGGL(recur_kernel, dim3(NBATCH / 4), dim3(64), 0, stream,
                       ws, Wf, Wi, Wu, Wo, out);
}